// Round 1
// baseline (365.417 us; speedup 1.0000x reference)
//
#include <hip/hip_runtime.h>
#include <hip/hip_bf16.h>

typedef __attribute__((ext_vector_type(8))) short short8;
typedef __attribute__((ext_vector_type(4))) float float4v;

#define L2E 1.44269504088896f

__device__ inline unsigned short f2bf_rne(float x) {
    unsigned int u = __float_as_uint(x);
    u += 0x7FFFu + ((u >> 16) & 1u);
    return (unsigned short)(u >> 16);
}
__device__ inline float bf2f(unsigned short h) {
    return __uint_as_float(((unsigned int)h) << 16);
}

// ---------------- K0a: split q,k into bf16 hi/lo ----------------
__global__ __launch_bounds__(256) void split_qk(
    const float* __restrict__ q, const float* __restrict__ k,
    unsigned short* __restrict__ qh, unsigned short* __restrict__ ql,
    unsigned short* __restrict__ kh, unsigned short* __restrict__ kl)
{
    const size_t n4 = (size_t)4096 * 1024 / 4;  // float4 groups per array
    size_t idx = (size_t)blockIdx.x * 256 + threadIdx.x;
    const float* src; unsigned short *dh, *dl; size_t base;
    if (idx < n4) { src = q; dh = qh; dl = ql; base = idx; }
    else          { src = k; dh = kh; dl = kl; base = idx - n4; }
    float4 xv = ((const float4*)src)[base];
    float xs[4] = {xv.x, xv.y, xv.z, xv.w};
    ushort4 hv, lv;
    unsigned short h;
    h = f2bf_rne(xs[0]); hv.x = h; lv.x = f2bf_rne(xs[0] - bf2f(h));
    h = f2bf_rne(xs[1]); hv.y = h; lv.y = f2bf_rne(xs[1] - bf2f(h));
    h = f2bf_rne(xs[2]); hv.z = h; lv.z = f2bf_rne(xs[2] - bf2f(h));
    h = f2bf_rne(xs[3]); hv.w = h; lv.w = f2bf_rne(xs[3] - bf2f(h));
    ((ushort4*)dh)[base] = hv;
    ((ushort4*)dl)[base] = lv;
}

// ---------------- K0b: transpose v -> vt bf16 [1024][4096] ----------------
__global__ __launch_bounds__(256) void transpose_v(
    const float* __restrict__ v, unsigned short* __restrict__ vt)
{
    __shared__ float tile[32][33];
    int k0 = blockIdx.x * 32;   // key block
    int d0 = blockIdx.y * 32;   // d block
    int tx = threadIdx.x & 31, ty = threadIdx.x >> 5;  // ty 0..7
#pragma unroll
    for (int i = 0; i < 4; ++i) {
        int r = ty + i * 8;
        tile[r][tx] = v[(size_t)(k0 + r) * 1024 + d0 + tx];
    }
    __syncthreads();
#pragma unroll
    for (int i = 0; i < 4; ++i) {
        int r = ty + i * 8;  // d index within tile
        vt[(size_t)(d0 + r) * 4096 + k0 + tx] = f2bf_rne(tile[tx][r]);
    }
}

// ---------------- K1: S = QK^T via split-bf16 (3 segments, K=1024 each) ----
__global__ __launch_bounds__(256) void gemm_s(
    const unsigned short* __restrict__ qh, const unsigned short* __restrict__ ql,
    const unsigned short* __restrict__ kh, const unsigned short* __restrict__ kl,
    float* __restrict__ S)
{
    __shared__ unsigned short As[128][72];  // 64 + 8 pad; row stride 144B (16B-aligned)
    __shared__ unsigned short Bs[128][72];
    int tid = threadIdx.x;
    int bx = blockIdx.x, by = blockIdx.y;
    int row0 = by * 128, col0 = bx * 128;
    int wave = tid >> 6, lane = tid & 63;
    int wr = (wave >> 1) * 64, wc = (wave & 1) * 64;
    int quad = lane >> 4, lrow = lane & 15;

    float4v acc[4][4];
#pragma unroll
    for (int mi = 0; mi < 4; ++mi)
#pragma unroll
        for (int ni = 0; ni < 4; ++ni) acc[mi][ni] = (float4v){0.f, 0.f, 0.f, 0.f};

    const unsigned short* segA[3] = {qh, ql, qh};
    const unsigned short* segB[3] = {kh, kh, kl};

    int srow = tid >> 3;        // 0..31
    int scol = (tid & 7) * 8;   // 0..56

    for (int seg = 0; seg < 3; ++seg) {
        const unsigned short* Ap = segA[seg];
        const unsigned short* Bp = segB[seg];
        for (int kc = 0; kc < 1024; kc += 64) {
            __syncthreads();
#pragma unroll
            for (int i = 0; i < 4; ++i) {
                int r = srow + 32 * i;
                *(uint4*)&As[r][scol] = *(const uint4*)&Ap[(size_t)(row0 + r) * 1024 + kc + scol];
                *(uint4*)&Bs[r][scol] = *(const uint4*)&Bp[(size_t)(col0 + r) * 1024 + kc + scol];
            }
            __syncthreads();
#pragma unroll
            for (int ks = 0; ks < 2; ++ks) {
                short8 af[4], bf[4];
#pragma unroll
                for (int mi = 0; mi < 4; ++mi)
                    af[mi] = *(const short8*)&As[wr + mi * 16 + lrow][ks * 32 + quad * 8];
#pragma unroll
                for (int ni = 0; ni < 4; ++ni)
                    bf[ni] = *(const short8*)&Bs[wc + ni * 16 + lrow][ks * 32 + quad * 8];
#pragma unroll
                for (int mi = 0; mi < 4; ++mi)
#pragma unroll
                    for (int ni = 0; ni < 4; ++ni)
                        acc[mi][ni] = __builtin_amdgcn_mfma_f32_16x16x32_bf16(
                            af[mi], bf[ni], acc[mi][ni], 0, 0, 0);
            }
        }
    }
#pragma unroll
    for (int mi = 0; mi < 4; ++mi)
#pragma unroll
        for (int ni = 0; ni < 4; ++ni)
#pragma unroll
            for (int r = 0; r < 4; ++r) {
                int row = row0 + wr + mi * 16 + quad * 4 + r;
                int col = col0 + wc + ni * 16 + lrow;
                S[(size_t)row * 4096 + col] = acc[mi][ni][r];
            }
}

// ---------------- K2: per-row max and 1/sum ----------------
__global__ __launch_bounds__(256) void row_stats(
    const float* __restrict__ S, float* __restrict__ mbuf, float* __restrict__ rbuf)
{
    int wave = threadIdx.x >> 6, lane = threadIdx.x & 63;
    int row = blockIdx.x * 4 + wave;
    const float* sp = &S[(size_t)row * 4096];
    float buf[64];
#pragma unroll
    for (int i = 0; i < 64; ++i) buf[i] = sp[lane + i * 64];
    float m = buf[0];
#pragma unroll
    for (int i = 1; i < 64; ++i) m = fmaxf(m, buf[i]);
#pragma unroll
    for (int off = 32; off > 0; off >>= 1) m = fmaxf(m, __shfl_xor(m, off));
    float s = 0.f;
#pragma unroll
    for (int i = 0; i < 64; ++i) s += exp2f((buf[i] - m) * L2E);
#pragma unroll
    for (int off = 32; off > 0; off >>= 1) s += __shfl_xor(s, off);
    if (lane == 0) { mbuf[row] = m; rbuf[row] = 1.0f / s; }
}

// ---------------- K3: O = exp(S - m) * V, scaled by 1/l in epilogue --------
__global__ __launch_bounds__(256) void gemm_pv(
    const float* __restrict__ S, const unsigned short* __restrict__ vt,
    const float* __restrict__ mbuf, const float* __restrict__ rbuf,
    float* __restrict__ out)
{
    __shared__ unsigned short Ps[128][72];
    __shared__ unsigned short Vs[128][72];
    int tid = threadIdx.x;
    int bx = blockIdx.x, by = blockIdx.y;
    int row0 = by * 128;        // Q rows
    int col0 = bx * 128;        // D cols
    int wave = tid >> 6, lane = tid & 63;
    int wr = (wave >> 1) * 64, wc = (wave & 1) * 64;
    int quad = lane >> 4, lrow = lane & 15;

    float4v acc[4][4];
#pragma unroll
    for (int mi = 0; mi < 4; ++mi)
#pragma unroll
        for (int ni = 0; ni < 4; ++ni) acc[mi][ni] = (float4v){0.f, 0.f, 0.f, 0.f};

    int srow = tid >> 3;
    int scol = (tid & 7) * 8;

    for (int kc = 0; kc < 4096; kc += 64) {
        __syncthreads();
#pragma unroll
        for (int i = 0; i < 4; ++i) {
            int r = srow + 32 * i;
            float mrow = mbuf[row0 + r];
            const float* sp = &S[(size_t)(row0 + r) * 4096 + kc + scol];
            float4 s0 = *(const float4*)sp;
            float4 s1 = *(const float4*)(sp + 4);
            ushort4 p0, p1;
            p0.x = f2bf_rne(exp2f((s0.x - mrow) * L2E));
            p0.y = f2bf_rne(exp2f((s0.y - mrow) * L2E));
            p0.z = f2bf_rne(exp2f((s0.z - mrow) * L2E));
            p0.w = f2bf_rne(exp2f((s0.w - mrow) * L2E));
            p1.x = f2bf_rne(exp2f((s1.x - mrow) * L2E));
            p1.y = f2bf_rne(exp2f((s1.y - mrow) * L2E));
            p1.z = f2bf_rne(exp2f((s1.z - mrow) * L2E));
            p1.w = f2bf_rne(exp2f((s1.w - mrow) * L2E));
            *(ushort4*)&Ps[r][scol] = p0;
            *(ushort4*)&Ps[r][scol + 4] = p1;
            *(uint4*)&Vs[r][scol] = *(const uint4*)&vt[(size_t)(col0 + r) * 4096 + kc + scol];
        }
        __syncthreads();
#pragma unroll
        for (int ks = 0; ks < 2; ++ks) {
            short8 af[4], bf[4];
#pragma unroll
            for (int mi = 0; mi < 4; ++mi)
                af[mi] = *(const short8*)&Ps[wr + mi * 16 + lrow][ks * 32 + quad * 8];
#pragma unroll
            for (int ni = 0; ni < 4; ++ni)
                bf[ni] = *(const short8*)&Vs[wc + ni * 16 + lrow][ks * 32 + quad * 8];
#pragma unroll
            for (int mi = 0; mi < 4; ++mi)
#pragma unroll
                for (int ni = 0; ni < 4; ++ni)
                    acc[mi][ni] = __builtin_amdgcn_mfma_f32_16x16x32_bf16(
                        af[mi], bf[ni], acc[mi][ni], 0, 0, 0);
        }
    }
#pragma unroll
    for (int mi = 0; mi < 4; ++mi)
#pragma unroll
        for (int ni = 0; ni < 4; ++ni)
#pragma unroll
            for (int r = 0; r < 4; ++r) {
                int row = row0 + wr + mi * 16 + quad * 4 + r;
                int col = col0 + wc + ni * 16 + lrow;
                out[(size_t)row * 1024 + col] = acc[mi][ni][r] * rbuf[row];
            }
}

// ---------------- Fallback (if workspace too small): naive per-row --------
__global__ __launch_bounds__(256) void attn_fallback(
    const float* __restrict__ q, const float* __restrict__ k,
    const float* __restrict__ v, float* __restrict__ out)
{
    __shared__ float qs[1024];
    __shared__ float ps[4096];
    __shared__ float red[256];
    int row = blockIdx.x, tid = threadIdx.x;
    for (int i = tid; i < 1024; i += 256) qs[i] = q[(size_t)row * 1024 + i];
    __syncthreads();
    for (int j = tid; j < 4096; j += 256) {
        const float* kr = &k[(size_t)j * 1024];
        float s = 0.f;
        for (int d = 0; d < 1024; ++d) s += qs[d] * kr[d];
        ps[j] = s;
    }
    __syncthreads();
    float m = -3.4e38f;
    for (int j = tid; j < 4096; j += 256) m = fmaxf(m, ps[j]);
    red[tid] = m; __syncthreads();
    for (int s2 = 128; s2 > 0; s2 >>= 1) {
        if (tid < s2) red[tid] = fmaxf(red[tid], red[tid + s2]);
        __syncthreads();
    }
    m = red[0]; __syncthreads();
    float l = 0.f;
    for (int j = tid; j < 4096; j += 256) {
        float p = exp2f((ps[j] - m) * L2E);
        ps[j] = p; l += p;
    }
    red[tid] = l; __syncthreads();
    for (int s2 = 128; s2 > 0; s2 >>= 1) {
        if (tid < s2) red[tid] += red[tid + s2];
        __syncthreads();
    }
    float rinv = 1.0f / red[0];
    __syncthreads();
    for (int c = tid; c < 1024; c += 256) {
        float o = 0.f;
        for (int j = 0; j < 4096; ++j) o += ps[j] * v[(size_t)j * 1024 + c];
        out[(size_t)row * 1024 + c] = o * rinv;
    }
}

extern "C" void kernel_launch(void* const* d_in, const int* in_sizes, int n_in,
                              void* d_out, int out_size, void* d_ws, size_t ws_size,
                              hipStream_t stream) {
    const float* q = (const float*)d_in[0];
    const float* k = (const float*)d_in[1];
    const float* v = (const float*)d_in[2];
    float* out = (float*)d_out;

    const size_t SZ_S  = (size_t)4096 * 4096 * 4;   // 64 MiB
    const size_t SZ_H  = (size_t)4096 * 1024 * 2;   // 8 MiB per bf16 array
    size_t off = 0;
    char* ws = (char*)d_ws;
    float*          Sbuf = (float*)(ws + off);           off += SZ_S;
    unsigned short* qh   = (unsigned short*)(ws + off);  off += SZ_H;
    unsigned short* ql   = (unsigned short*)(ws + off);  off += SZ_H;
    unsigned short* kh   = (unsigned short*)(ws + off);  off += SZ_H;
    unsigned short* kl   = (unsigned short*)(ws + off);  off += SZ_H;
    unsigned short* vt   = (unsigned short*)(ws + off);  off += SZ_H;
    float*          mbuf = (float*)(ws + off);           off += 4096 * 4;
    float*          rbuf = (float*)(ws + off);           off += 4096 * 4;

    if (ws_size < off) {
        // Emergency slow path: no workspace needed.
        attn_fallback<<<4096, 256, 0, stream>>>(q, k, v, out);
        return;
    }

    split_qk<<<8192, 256, 0, stream>>>(q, k, qh, ql, kh, kl);
    transpose_v<<<dim3(128, 32), 256, 0, stream>>>(v, vt);
    gemm_s<<<dim3(32, 32), 256, 0, stream>>>(qh, ql, kh, kl, Sbuf);
    row_stats<<<1024, 256, 0, stream>>>(Sbuf, mbuf, rbuf);
    gemm_pv<<<dim3(8, 32), 256, 0, stream>>>(Sbuf, vt, mbuf, rbuf, out);
}

// Round 2
// 285.635 us; speedup vs baseline: 1.2793x; 1.2793x over previous
//
#include <hip/hip_runtime.h>
#include <hip/hip_bf16.h>

typedef __attribute__((ext_vector_type(8))) short short8;
typedef __attribute__((ext_vector_type(4))) float float4v;
typedef __attribute__((ext_vector_type(8))) _Float16 half8;

#define L2E 1.44269504088896f

__device__ inline unsigned short f2bf_rne(float x) {
    unsigned int u = __float_as_uint(x);
    u += 0x7FFFu + ((u >> 16) & 1u);
    return (unsigned short)(u >> 16);
}
__device__ inline float bf2f(unsigned short h) {
    return __uint_as_float(((unsigned int)h) << 16);
}

// Direct global->LDS DMA, 16B per lane. LDS dest = wave-uniform base + lane*16.
__device__ inline void gload_lds16(const unsigned short* g, unsigned short* l) {
    __builtin_amdgcn_global_load_lds(
        (const __attribute__((address_space(1))) void*)g,
        (__attribute__((address_space(3))) void*)l, 16, 0, 0);
}

// ---------------- K0a: split q,k into bf16 hi/lo ----------------
__global__ __launch_bounds__(256) void split_qk(
    const float* __restrict__ q, const float* __restrict__ k,
    unsigned short* __restrict__ qh, unsigned short* __restrict__ ql,
    unsigned short* __restrict__ kh, unsigned short* __restrict__ kl)
{
    const size_t n4 = (size_t)4096 * 1024 / 4;
    size_t idx = (size_t)blockIdx.x * 256 + threadIdx.x;
    const float* src; unsigned short *dh, *dl; size_t base;
    if (idx < n4) { src = q; dh = qh; dl = ql; base = idx; }
    else          { src = k; dh = kh; dl = kl; base = idx - n4; }
    float4 xv = ((const float4*)src)[base];
    float xs[4] = {xv.x, xv.y, xv.z, xv.w};
    ushort4 hv, lv;
    unsigned short h;
    h = f2bf_rne(xs[0]); hv.x = h; lv.x = f2bf_rne(xs[0] - bf2f(h));
    h = f2bf_rne(xs[1]); hv.y = h; lv.y = f2bf_rne(xs[1] - bf2f(h));
    h = f2bf_rne(xs[2]); hv.z = h; lv.z = f2bf_rne(xs[2] - bf2f(h));
    h = f2bf_rne(xs[3]); hv.w = h; lv.w = f2bf_rne(xs[3] - bf2f(h));
    ((ushort4*)dh)[base] = hv;
    ((ushort4*)dl)[base] = lv;
}

// ---------------- K0b: transpose v -> vt bf16 [1024][4096] ----------------
__global__ __launch_bounds__(256) void transpose_v(
    const float* __restrict__ v, unsigned short* __restrict__ vt)
{
    __shared__ float tile[32][33];
    int k0 = blockIdx.x * 32;
    int d0 = blockIdx.y * 32;
    int tx = threadIdx.x & 31, ty = threadIdx.x >> 5;
#pragma unroll
    for (int i = 0; i < 4; ++i) {
        int r = ty + i * 8;
        tile[r][tx] = v[(size_t)(k0 + r) * 1024 + d0 + tx];
    }
    __syncthreads();
#pragma unroll
    for (int i = 0; i < 4; ++i) {
        int r = ty + i * 8;
        vt[(size_t)(d0 + r) * 4096 + k0 + tx] = f2bf_rne(tile[tx][r]);
    }
}

// ---------------- K1: S = QK^T (3 bf16 segments), fused exp + strip stats --
// LDS layout per operand: [128 rows][64 k] bf16, 16B blocks XOR-swizzled:
// physical_block = logical_block ^ (row & 7). Staged by global_load_lds.
__global__ __launch_bounds__(256) void gemm_s(
    const unsigned short* __restrict__ qh, const unsigned short* __restrict__ ql,
    const unsigned short* __restrict__ kh, const unsigned short* __restrict__ kl,
    _Float16* __restrict__ Pl, float* __restrict__ pmax, float* __restrict__ psum)
{
    __shared__ unsigned short As[128 * 64];
    __shared__ unsigned short Bs[128 * 64];
    int tid = threadIdx.x;
    int bx = blockIdx.x, by = blockIdx.y;
    int row0 = by * 128, col0 = bx * 128;
    int wave = tid >> 6, lane = tid & 63;
    int wr = (wave >> 1) * 64, wc = (wave & 1) * 64;
    int quad = lane >> 4, lrow = lane & 15;
    int sr = lane >> 3, lb = (lane & 7) ^ sr;   // staging: sub-row, logical block
    int swz = lrow & 7;

    float4v acc[4][4];
#pragma unroll
    for (int mi = 0; mi < 4; ++mi)
#pragma unroll
        for (int ni = 0; ni < 4; ++ni) acc[mi][ni] = (float4v){0.f, 0.f, 0.f, 0.f};

    const unsigned short* segA[3] = {qh, ql, qh};
    const unsigned short* segB[3] = {kh, kh, kl};

    unsigned short* lA = As + wave * 32 * 64;
    unsigned short* lB = Bs + wave * 32 * 64;

    for (int seg = 0; seg < 3; ++seg) {
        const unsigned short* gA = segA[seg] + (size_t)(row0 + wave * 32 + sr) * 1024 + lb * 8;
        const unsigned short* gB = segB[seg] + (size_t)(col0 + wave * 32 + sr) * 1024 + lb * 8;
        for (int kc = 0; kc < 1024; kc += 64) {
            __syncthreads();
#pragma unroll
            for (int j = 0; j < 4; ++j) {
                gload_lds16(gA + j * 8 * 1024 + kc, lA + j * 8 * 64);
                gload_lds16(gB + j * 8 * 1024 + kc, lB + j * 8 * 64);
            }
            __syncthreads();
#pragma unroll
            for (int ks = 0; ks < 2; ++ks) {
                short8 af[4], bf[4];
                int bo = ((ks * 4 + quad) ^ swz) * 8;
#pragma unroll
                for (int mi = 0; mi < 4; ++mi)
                    af[mi] = *(const short8*)&As[(wr + mi * 16 + lrow) * 64 + bo];
#pragma unroll
                for (int ni = 0; ni < 4; ++ni)
                    bf[ni] = *(const short8*)&Bs[(wc + ni * 16 + lrow) * 64 + bo];
#pragma unroll
                for (int mi = 0; mi < 4; ++mi)
#pragma unroll
                    for (int ni = 0; ni < 4; ++ni)
                        acc[mi][ni] = __builtin_amdgcn_mfma_f32_16x16x32_bf16(
                            af[mi], bf[ni], acc[mi][ni], 0, 0, 0);
            }
        }
    }

    // Epilogue: per row, strip(64 cols)-local softmax numerator in fp16 + partials.
    int strip = bx * 2 + (wave & 1);
#pragma unroll
    for (int mi = 0; mi < 4; ++mi)
#pragma unroll
        for (int r = 0; r < 4; ++r) {
            int row = row0 + wr + mi * 16 + quad * 4 + r;
            float v[4];
#pragma unroll
            for (int ni = 0; ni < 4; ++ni) v[ni] = acc[mi][ni][r];
            float mx = fmaxf(fmaxf(v[0], v[1]), fmaxf(v[2], v[3]));
#pragma unroll
            for (int d = 1; d < 16; d <<= 1) mx = fmaxf(mx, __shfl_xor(mx, d));
            float p[4], s = 0.f;
#pragma unroll
            for (int ni = 0; ni < 4; ++ni) { p[ni] = exp2f((v[ni] - mx) * L2E); s += p[ni]; }
#pragma unroll
            for (int d = 1; d < 16; d <<= 1) s += __shfl_xor(s, d);
#pragma unroll
            for (int ni = 0; ni < 4; ++ni)
                Pl[(size_t)row * 4096 + col0 + wc + ni * 16 + lrow] = (_Float16)p[ni];
            if (lrow == 0) { pmax[row * 64 + strip] = mx; psum[row * 64 + strip] = s; }
        }
}

// ---------------- K2: combine strip partials -> scale[row][strip] ----------
__global__ __launch_bounds__(256) void combine(
    const float* __restrict__ pmax, const float* __restrict__ psum,
    float* __restrict__ scale)
{
    int row = blockIdx.x * 4 + (threadIdx.x >> 6);
    int lane = threadIdx.x & 63;
    float m = pmax[row * 64 + lane];
    float s = psum[row * 64 + lane];
    float M = m;
#pragma unroll
    for (int d = 1; d < 64; d <<= 1) M = fmaxf(M, __shfl_xor(M, d));
    float e = exp2f((m - M) * L2E);
    float ls = s * e;
#pragma unroll
    for (int d = 1; d < 64; d <<= 1) ls += __shfl_xor(ls, d);
    scale[row * 64 + lane] = e / ls;
}

// ---------------- K2b: in-place rescale fp16 -> final bf16 attn weights ----
__global__ __launch_bounds__(256) void rescale(
    unsigned short* __restrict__ Pbuf, const float* __restrict__ scale)
{
    size_t g = (size_t)blockIdx.x * 256 + threadIdx.x;  // one 8-element group
    size_t base = g * 8;
    int row = (int)(base >> 12);
    int col = (int)(base & 4095);
    float sc = scale[row * 64 + (col >> 6)];
    half8 hp = *(const half8*)&Pbuf[base];
    ushort4 o0, o1;
    o0.x = f2bf_rne((float)hp[0] * sc);
    o0.y = f2bf_rne((float)hp[1] * sc);
    o0.z = f2bf_rne((float)hp[2] * sc);
    o0.w = f2bf_rne((float)hp[3] * sc);
    o1.x = f2bf_rne((float)hp[4] * sc);
    o1.y = f2bf_rne((float)hp[5] * sc);
    o1.z = f2bf_rne((float)hp[6] * sc);
    o1.w = f2bf_rne((float)hp[7] * sc);
    *(ushort4*)&Pbuf[base] = o0;
    *(ushort4*)&Pbuf[base + 4] = o1;
}

// ---------------- K3: O = P(bf16) * Vt, pure GEMM, K=4096 ----------------
__global__ __launch_bounds__(256) void gemm_pv(
    const unsigned short* __restrict__ P, const unsigned short* __restrict__ vt,
    float* __restrict__ out)
{
    __shared__ unsigned short As[128 * 64];
    __shared__ unsigned short Bs[128 * 64];
    int tid = threadIdx.x;
    int bx = blockIdx.x, by = blockIdx.y;
    int row0 = by * 128, col0 = bx * 128;
    int wave = tid >> 6, lane = tid & 63;
    int wr = (wave >> 1) * 64, wc = (wave & 1) * 64;
    int quad = lane >> 4, lrow = lane & 15;
    int sr = lane >> 3, lb = (lane & 7) ^ sr;
    int swz = lrow & 15 & 7;

    float4v acc[4][4];
#pragma unroll
    for (int mi = 0; mi < 4; ++mi)
#pragma unroll
        for (int ni = 0; ni < 4; ++ni) acc[mi][ni] = (float4v){0.f, 0.f, 0.f, 0.f};

    unsigned short* lA = As + wave * 32 * 64;
    unsigned short* lB = Bs + wave * 32 * 64;
    const unsigned short* gA = P  + (size_t)(row0 + wave * 32 + sr) * 4096 + lb * 8;
    const unsigned short* gB = vt + (size_t)(col0 + wave * 32 + sr) * 4096 + lb * 8;

    for (int kc = 0; kc < 4096; kc += 64) {
        __syncthreads();
#pragma unroll
        for (int j = 0; j < 4; ++j) {
            gload_lds16(gA + j * 8 * 4096 + kc, lA + j * 8 * 64);
            gload_lds16(gB + j * 8 * 4096 + kc, lB + j * 8 * 64);
        }
        __syncthreads();
#pragma unroll
        for (int ks = 0; ks < 2; ++ks) {
            short8 af[4], bf[4];
            int bo = ((ks * 4 + quad) ^ swz) * 8;
#pragma unroll
            for (int mi = 0; mi < 4; ++mi)
                af[mi] = *(const short8*)&As[(wr + mi * 16 + lrow) * 64 + bo];
#pragma unroll
            for (int ni = 0; ni < 4; ++ni)
                bf[ni] = *(const short8*)&Bs[(wc + ni * 16 + lrow) * 64 + bo];
#pragma unroll
            for (int mi = 0; mi < 4; ++mi)
#pragma unroll
                for (int ni = 0; ni < 4; ++ni)
                    acc[mi][ni] = __builtin_amdgcn_mfma_f32_16x16x32_bf16(
                        af[mi], bf[ni], acc[mi][ni], 0, 0, 0);
        }
    }
#pragma unroll
    for (int mi = 0; mi < 4; ++mi)
#pragma unroll
        for (int ni = 0; ni < 4; ++ni)
#pragma unroll
            for (int r = 0; r < 4; ++r) {
                int row = row0 + wr + mi * 16 + quad * 4 + r;
                int col = col0 + wc + ni * 16 + lrow;
                out[(size_t)row * 1024 + col] = acc[mi][ni][r];
            }
}

// ---------------- Fallback (if workspace too small): naive per-row --------
__global__ __launch_bounds__(256) void attn_fallback(
    const float* __restrict__ q, const float* __restrict__ k,
    const float* __restrict__ v, float* __restrict__ out)
{
    __shared__ float qs[1024];
    __shared__ float ps[4096];
    __shared__ float red[256];
    int row = blockIdx.x, tid = threadIdx.x;
    for (int i = tid; i < 1024; i += 256) qs[i] = q[(size_t)row * 1024 + i];
    __syncthreads();
    for (int j = tid; j < 4096; j += 256) {
        const float* kr = &k[(size_t)j * 1024];
        float s = 0.f;
        for (int d = 0; d < 1024; ++d) s += qs[d] * kr[d];
        ps[j] = s;
    }
    __syncthreads();
    float m = -3.4e38f;
    for (int j = tid; j < 4096; j += 256) m = fmaxf(m, ps[j]);
    red[tid] = m; __syncthreads();
    for (int s2 = 128; s2 > 0; s2 >>= 1) {
        if (tid < s2) red[tid] = fmaxf(red[tid], red[tid + s2]);
        __syncthreads();
    }
    m = red[0]; __syncthreads();
    float l = 0.f;
    for (int j = tid; j < 4096; j += 256) {
        float p = exp2f((ps[j] - m) * L2E);
        ps[j] = p; l += p;
    }
    red[tid] = l; __syncthreads();
    for (int s2 = 128; s2 > 0; s2 >>= 1) {
        if (tid < s2) red[tid] += red[tid + s2];
        __syncthreads();
    }
    float rinv = 1.0f / red[0];
    __syncthreads();
    for (int c = tid; c < 1024; c += 256) {
        float o = 0.f;
        for (int j = 0; j < 4096; ++j) o += ps[j] * v[(size_t)j * 1024 + c];
        out[(size_t)row * 1024 + c] = o * rinv;
    }
}

extern "C" void kernel_launch(void* const* d_in, const int* in_sizes, int n_in,
                              void* d_out, int out_size, void* d_ws, size_t ws_size,
                              hipStream_t stream) {
    const float* q = (const float*)d_in[0];
    const float* k = (const float*)d_in[1];
    const float* v = (const float*)d_in[2];
    float* out = (float*)d_out;

    const size_t SZ_P = (size_t)4096 * 4096 * 2;   // 32 MiB (fp16 then bf16, in place)
    const size_t SZ_H = (size_t)4096 * 1024 * 2;   // 8 MiB per bf16 array
    const size_t SZ_T = (size_t)4096 * 64 * 4;     // 1 MiB per stats table
    size_t off = 0;
    char* ws = (char*)d_ws;
    unsigned short* Pbuf = (unsigned short*)(ws + off); off += SZ_P;
    unsigned short* qh   = (unsigned short*)(ws + off); off += SZ_H;
    unsigned short* ql   = (unsigned short*)(ws + off); off += SZ_H;
    unsigned short* kh   = (unsigned short*)(ws + off); off += SZ_H;
    unsigned short* kl   = (unsigned short*)(ws + off); off += SZ_H;
    unsigned short* vt   = (unsigned short*)(ws + off); off += SZ_H;
    float*          pmax = (float*)(ws + off);          off += SZ_T;
    float*          psum = (float*)(ws + off);          off += SZ_T;
    float*          scl  = (float*)(ws + off);          off += SZ_T;

    if (ws_size < off) {
        attn_fallback<<<4096, 256, 0, stream>>>(q, k, v, out);
        return;
    }

    split_qk<<<8192, 256, 0, stream>>>(q, k, qh, ql, kh, kl);
    transpose_v<<<dim3(128, 32), 256, 0, stream>>>(v, vt);
    gemm_s<<<dim3(32, 32), 256, 0, stream>>>(qh, ql, kh, kl,
                                             (_Float16*)Pbuf, pmax, psum);
    combine<<<1024, 256, 0, stream>>>(pmax, psum, scl);
    rescale<<<8192, 256, 0, stream>>>(Pbuf, scl);
    gemm_pv<<<dim3(8, 32), 256, 0, stream>>>(Pbuf, vt, out);
}